// Round 8
// baseline (238.650 us; speedup 1.0000x reference)
//
#include <hip/hip_runtime.h>
#include <math.h>

#define EPS 1e-5f

typedef __attribute__((ext_vector_type(8))) short s16x8;   // 8 bf16 (4 VGPRs)
typedef __attribute__((ext_vector_type(4))) float f32x4;   // MFMA C/D

__device__ __forceinline__ unsigned short f2bf(float x) {
    unsigned u = __float_as_uint(x);
    u += 0x7fffu + ((u >> 16) & 1u);           // round-to-nearest-even
    return (unsigned short)(u >> 16);
}
__device__ __forceinline__ float bf2f(unsigned short h) {
    return __uint_as_float(((unsigned)h) << 16);
}
__device__ __forceinline__ unsigned long long pack4bf(float a, float b, float c, float d) {
    return (unsigned long long)f2bf(a)
         | ((unsigned long long)f2bf(b) << 16)
         | ((unsigned long long)f2bf(c) << 32)
         | ((unsigned long long)f2bf(d) << 48);
}

// ---------------------------------------------------------------- K1: conv1 + knn + (fused) weight bf16 conversion
// h1b bf16 [b][l][c]. grid 1024 + 2304 (weight-convert blocks).
__global__ __launch_bounds__(128) void k1_conv1_knn(
    const float* __restrict__ pg, const float* __restrict__ W1,
    const float* __restrict__ b1,
    const float* __restrict__ W2, const float* __restrict__ W3,
    const float* __restrict__ W4, const float* __restrict__ Wf,
    unsigned short* __restrict__ h1b, float* __restrict__ p1s, float* __restrict__ p1q,
    int* __restrict__ idxw,
    unsigned short* __restrict__ W2b, unsigned short* __restrict__ W3b,
    unsigned short* __restrict__ W4b, unsigned short* __restrict__ Wfb)
{
    __shared__ float pgs[96];
    __shared__ float sqs[32];
    if (blockIdx.x >= 1024) {
        const int i = (blockIdx.x - 1024) * 128 + threadIdx.x;
        if (i < 32768)  W2b[i] = f2bf(W2[i]);
        if (i < 262144) W3b[i] = f2bf(W3[i]);
        if (i < 196608) W4b[i] = f2bf(W4[i]);
        if (i < 294912) Wfb[i] = f2bf(Wf[i]);
        return;
    }
    const int b = blockIdx.x;
    const int t = threadIdx.x;
    if (t < 96) pgs[t] = pg[b * 96 + t];
    __syncthreads();
    if (t < 32) {
        float x = pgs[t*3+0], y = pgs[t*3+1], z = pgs[t*3+2];
        sqs[t] = x*x + y*y + z*z;
    }
    __syncthreads();
    {
        const float w0 = W1[t*3+0], w1 = W1[t*3+1], w2 = W1[t*3+2];
        const float bb = b1[t];
        float s = 0.f, q = 0.f;
        unsigned short* hcol = h1b + (size_t)b*4096 + t;
        #pragma unroll
        for (int l = 0; l < 32; ++l) {
            float v = fmaf(w2, pgs[l*3+2], fmaf(w1, pgs[l*3+1], fmaf(w0, pgs[l*3+0], bb)));
            hcol[l*128] = f2bf(v); s += v; q += v*v;
        }
        p1s[b*128 + t] = s;
        p1q[b*128 + t] = q;
    }
    if (t < 32) {
        const float xl = pgs[t*3+0], yl = pgs[t*3+1], zl = pgs[t*3+2];
        const float sql = sqs[t];
        float dist[32];
        #pragma unroll
        for (int m = 0; m < 32; ++m) {
            float dot = xl*pgs[m*3+0] + yl*pgs[m*3+1] + zl*pgs[m*3+2];
            dist[m] = sql + sqs[m] - 2.f*dot;
        }
        unsigned used = 0u;
        int* orow = idxw + b*256 + t*8;
        #pragma unroll
        for (int j = 0; j < 8; ++j) {
            float best = 3.4e38f; int bi = 0;
            #pragma unroll
            for (int m = 0; m < 32; ++m) {
                if (!((used >> m) & 1u) && dist[m] < best) { best = dist[m]; bi = m; }
            }
            used |= (1u << bi);
            orow[j] = bi;
        }
    }
}

// ---------------------------------------------------------------- BN finalize, partials [part][chan], 4 channels/block
__global__ __launch_bounds__(256) void k_bn_fin2(
    const float* __restrict__ ps, const float* __restrict__ pq,
    int nPart, int nChan, float invN,
    const float* __restrict__ gamma, const float* __restrict__ beta,
    float* __restrict__ scale, float* __restrict__ shift)
{
    const int ob = blockIdx.x * 4;
    const int t = threadIdx.x;
    const int co = t & 3, i0 = t >> 2;
    float s = 0.f, q = 0.f;
    for (int i = i0; i < nPart; i += 64) {
        s += ps[(size_t)i*nChan + ob + co];
        q += pq[(size_t)i*nChan + ob + co];
    }
    #pragma unroll
    for (int off = 32; off >= 4; off >>= 1) {
        s += __shfl_down(s, off, 64);
        q += __shfl_down(q, off, 64);
    }
    __shared__ float ss[4][4], qs[4][4];
    const int wid = t >> 6, lane = t & 63;
    if (lane < 4) { ss[wid][lane] = s; qs[wid][lane] = q; }
    __syncthreads();
    if (t < 4) {
        float S = ss[0][t] + ss[1][t] + ss[2][t] + ss[3][t];
        float Q = qs[0][t] + qs[1][t] + qs[2][t] + qs[3][t];
        const int o = ob + t;
        float mu  = S * invN;
        float var = Q * invN - mu*mu;
        float sc  = gamma[o] * rsqrtf(var + EPS);
        scale[o] = sc;
        shift[o] = beta[o] - mu * sc;
    }
}

// ---------------------------------------------------------------- K3 v3: 2 groups/block, 16 waves (1024 thr).
// conv2 (K=128) -> fg-bias GEMM -> conv3 main (K=256). 2 blocks/CU = 32 waves/CU.
__global__ __launch_bounds__(1024, 2) void k3_mfma(
    const unsigned short* __restrict__ h1b,
    const float* __restrict__ scale1, const float* __restrict__ shift1,
    const unsigned short* __restrict__ W2b, const float* __restrict__ b2,
    const unsigned short* __restrict__ W3b, const float* __restrict__ b3,
    unsigned short* __restrict__ h3b, float* __restrict__ p3s, float* __restrict__ p3q)
{
    const int g0 = blockIdx.x * 2;
    const int t = threadIdx.x;
    __shared__ __align__(16) unsigned short SB[19472];
    unsigned short* B1  = SB;            // [64][136] conv2 staging (dead after conv2)
    unsigned short* F2  = SB;            // [64][264] f2, conv3 B-matrix
    unsigned short* FGB = SB + 16896;    // [2][264] fg per group (bf16)
    float* FGR = (float*)(SB + 17424);   // [512][2] fg-bias result fp32

    // ---- P0: stage x1 = relu(BN1(h1b)) bf16 [l64][c128]; 1 x 16B chunk per thread
    {
        const int l = t >> 4, c0 = (t & 15) * 8;
        const int g = g0 + (l >> 5);
        s16x8 hv = *(const s16x8*)(h1b + (size_t)g*4096 + (l & 31)*128 + c0);
        unsigned short ov[8];
        #pragma unroll
        for (int e = 0; e < 8; ++e) {
            int c = c0 + e;
            float v = fmaxf(fmaf(bf2f((unsigned short)hv[e]), scale1[c], shift1[c]), 0.f);
            ov[e] = f2bf(v);
        }
        uint4 o4;
        o4.x = (unsigned)ov[0] | ((unsigned)ov[1] << 16);
        o4.y = (unsigned)ov[2] | ((unsigned)ov[3] << 16);
        o4.z = (unsigned)ov[4] | ((unsigned)ov[5] << 16);
        o4.w = (unsigned)ov[6] | ((unsigned)ov[7] << 16);
        *(uint4*)&B1[l*136 + c0] = o4;
    }
    __syncthreads();

    const int wave = t >> 6;      // 0..15
    const int lane = t & 63;
    const int m    = lane & 15;
    const int quad = lane >> 4;

    // ---- P1: conv2 MFMA: M=256 (1 mt/wave), N=64, K=128
    f32x4 acc2[4];
    #pragma unroll
    for (int n = 0; n < 4; ++n) acc2[n] = (f32x4){0.f, 0.f, 0.f, 0.f};

    #pragma unroll
    for (int kt = 0; kt < 4; ++kt) {
        s16x8 bv[4];
        #pragma unroll
        for (int nt = 0; nt < 4; ++nt)
            bv[nt] = *(const s16x8*)&B1[(nt*16 + m)*136 + kt*32 + quad*8];
        s16x8 av = *(const s16x8*)(W2b + (size_t)(wave*16 + m)*128 + kt*32 + quad*8);
        #pragma unroll
        for (int nt = 0; nt < 4; ++nt)
            acc2[nt] = __builtin_amdgcn_mfma_f32_16x16x32_bf16(av, bv[nt], acc2[nt], 0, 0, 0);
    }
    __syncthreads();   // B1 dead; SB becomes F2

    // ---- P2: epilogue conv2: bias, write f2 cols, fg into FGB
    {
        const int o0 = wave*16 + quad*4;
        #pragma unroll
        for (int r = 0; r < 4; ++r) {
            float bb = b2[o0 + r];
            #pragma unroll
            for (int nt = 0; nt < 4; ++nt) acc2[nt][r] += bb;
        }
        #pragma unroll
        for (int nt = 0; nt < 4; ++nt) {
            const int row = nt*16 + m;
            *(unsigned long long*)&F2[row*264 + o0] =
                pack4bf(acc2[nt][0], acc2[nt][1], acc2[nt][2], acc2[nt][3]);
        }
        float f0[4], f1[4];
        #pragma unroll
        for (int r = 0; r < 4; ++r) {
            f0[r] = fmaxf(acc2[0][r], acc2[1][r]);
            f1[r] = fmaxf(acc2[2][r], acc2[3][r]);
        }
        #pragma unroll
        for (int msk = 1; msk < 16; msk <<= 1)
            #pragma unroll
            for (int r = 0; r < 4; ++r) {
                f0[r] = fmaxf(f0[r], __shfl_xor(f0[r], msk, 16));
                f1[r] = fmaxf(f1[r], __shfl_xor(f1[r], msk, 16));
            }
        if (m == 0) {
            *(unsigned long long*)&FGB[o0]       = pack4bf(f0[0], f0[1], f0[2], f0[3]);
            *(unsigned long long*)&FGB[264 + o0] = pack4bf(f1[0], f1[1], f1[2], f1[3]);
        }
    }
    __syncthreads();

    // ---- P3: fg-bias GEMM: fgb[o][g] = W3[:, :256] . fg[g]; 2 tiles/wave, K=256
    {
        f32x4 facc[2];
        #pragma unroll
        for (int i = 0; i < 2; ++i) facc[i] = (f32x4){0.f, 0.f, 0.f, 0.f};
        #pragma unroll
        for (int kt = 0; kt < 8; ++kt) {
            s16x8 bg = *(const s16x8*)&FGB[(m & 1)*264 + kt*32 + quad*8];
            #pragma unroll
            for (int i = 0; i < 2; ++i) {
                s16x8 av = *(const s16x8*)(W3b + (size_t)((wave*2 + i)*16 + m)*512 + kt*32 + quad*8);
                facc[i] = __builtin_amdgcn_mfma_f32_16x16x32_bf16(av, bg, facc[i], 0, 0, 0);
            }
        }
        if (m < 2) {
            #pragma unroll
            for (int i = 0; i < 2; ++i)
                #pragma unroll
                for (int r = 0; r < 4; ++r)
                    FGR[((wave*2 + i)*16 + quad*4 + r)*2 + m] = facc[i][r];
        }
    }
    __syncthreads();

    // ---- P4: conv3 main: 2 mt/wave, N=64, K=256; acc init = b3 + fgb
    f32x4 acc3[2][4];
    #pragma unroll
    for (int mt = 0; mt < 2; ++mt) {
        const int ob = (wave*2 + mt)*16 + quad*4;
        #pragma unroll
        for (int r = 0; r < 4; ++r) {
            float2 fb = *(const float2*)&FGR[(ob + r)*2];
            float bb = b3[ob + r];
            acc3[mt][0][r] = bb + fb.x;
            acc3[mt][1][r] = bb + fb.x;
            acc3[mt][2][r] = bb + fb.y;
            acc3[mt][3][r] = bb + fb.y;
        }
    }
    #pragma unroll
    for (int kt = 0; kt < 8; ++kt) {
        s16x8 bv[4];
        #pragma unroll
        for (int nt = 0; nt < 4; ++nt)
            bv[nt] = *(const s16x8*)&F2[(nt*16 + m)*264 + kt*32 + quad*8];
        #pragma unroll
        for (int mt = 0; mt < 2; ++mt) {
            s16x8 av = *(const s16x8*)(W3b + (size_t)((wave*2 + mt)*16 + m)*512 + 256 + kt*32 + quad*8);
            #pragma unroll
            for (int nt = 0; nt < 4; ++nt)
                acc3[mt][nt] = __builtin_amdgcn_mfma_f32_16x16x32_bf16(av, bv[nt], acc3[mt][nt], 0, 0, 0);
        }
    }

    // ---- epilogue: fragment-order h3b store (o-tile ot = wave*2+mt, same flat layout) + stats
    unsigned short* dst = h3b + (size_t)blockIdx.x * 32768;
    #pragma unroll
    for (int mt = 0; mt < 2; ++mt) {
        const int ot = wave*2 + mt;
        const int o0 = ot*16 + quad*4;
        float s0[4], q0[4], s1[4], q1[4];
        #pragma unroll
        for (int r = 0; r < 4; ++r) {
            s0[r] = acc3[mt][0][r] + acc3[mt][1][r];
            q0[r] = acc3[mt][0][r]*acc3[mt][0][r] + acc3[mt][1][r]*acc3[mt][1][r];
            s1[r] = acc3[mt][2][r] + acc3[mt][3][r];
            q1[r] = acc3[mt][2][r]*acc3[mt][2][r] + acc3[mt][3][r]*acc3[mt][3][r];
        }
        {
            unsigned long long u0 = pack4bf(acc3[mt][0][0], acc3[mt][0][1], acc3[mt][0][2], acc3[mt][0][3]);
            unsigned long long u1 = pack4bf(acc3[mt][1][0], acc3[mt][1][1], acc3[mt][1][2], acc3[mt][1][3]);
            unsigned long long u2 = pack4bf(acc3[mt][2][0], acc3[mt][2][1], acc3[mt][2][2], acc3[mt][2][3]);
            unsigned long long u3 = pack4bf(acc3[mt][3][0], acc3[mt][3][1], acc3[mt][3][2], acc3[mt][3][3]);
            unsigned short* p = dst + (size_t)(ot*64 + lane) * 16;
            *(uint4*)(p)     = make_uint4((unsigned)u0, (unsigned)(u0 >> 32), (unsigned)u1, (unsigned)(u1 >> 32));
            *(uint4*)(p + 8) = make_uint4((unsigned)u2, (unsigned)(u2 >> 32), (unsigned)u3, (unsigned)(u3 >> 32));
        }
        #pragma unroll
        for (int msk = 1; msk < 16; msk <<= 1)
            #pragma unroll
            for (int r = 0; r < 4; ++r) {
                s0[r] += __shfl_xor(s0[r], msk, 16);
                q0[r] += __shfl_xor(q0[r], msk, 16);
                s1[r] += __shfl_xor(s1[r], msk, 16);
                q1[r] += __shfl_xor(q1[r], msk, 16);
            }
        if (m == 0) {
            #pragma unroll
            for (int r = 0; r < 4; ++r) {
                p3s[(size_t)g0*512 + o0 + r]       = s0[r];
                p3q[(size_t)g0*512 + o0 + r]       = q0[r];
                p3s[(size_t)(g0+1)*512 + o0 + r]   = s1[r];
                p3q[(size_t)(g0+1)*512 + o0 + r]   = q1[r];
            }
        }
    }
}

// ---------------------------------------------------------------- K5: 2 groups/block, 12 waves. MFMA conv4 + fg2 + algebraic knn branch.
__global__ __launch_bounds__(768, 2) void k5_mfma(
    const unsigned short* __restrict__ h3b,
    const float* __restrict__ scale3, const float* __restrict__ shift3,
    const unsigned short* __restrict__ W4b, const float* __restrict__ b4,
    const int* __restrict__ idxw,
    float* __restrict__ fg2, float* __restrict__ A,
    float* __restrict__ S1p, float* __restrict__ S2p)
{
    const int g0 = blockIdx.x * 2;
    const int t = threadIdx.x;
    __shared__ __align__(16) unsigned short SB[33280];   // 66560 B
    unsigned short* B4 = SB;                              // [64][520] staging
    unsigned short* XT = SB;                              // [g][o*40 + l], g stride 15360
    unsigned short* Mm = SB + 30720;                      // [g][l*40 + m], g stride 1280
    __shared__ int icnt[2][32];
    __shared__ float r1[2][12], r2[2][12];

    {
        const uint4* src = (const uint4*)(h3b + (size_t)blockIdx.x * 32768);
        for (int i = t; i < 4096; i += 768) {
            uint4 hv = src[i];
            const int flat16 = i >> 1, half = i & 1;
            const int ln = flat16 & 63, m2 = ln & 15, q2 = ln >> 4;
            const int wm = flat16 >> 6;
            const int o0 = (wm >> 2)*64 + (wm & 3)*16 + q2*4;   // == wm*16 + q2*4
            const float4 sc = *(const float4*)(scale3 + o0);
            const float4 sh = *(const float4*)(shift3 + o0);
            const int rowa = (half*2)*16 + m2;
            float a0 = fmaxf(fmaf(bf2f((unsigned short)(hv.x       )), sc.x, sh.x), 0.f);
            float a1 = fmaxf(fmaf(bf2f((unsigned short)(hv.x >> 16 )), sc.y, sh.y), 0.f);
            float a2 = fmaxf(fmaf(bf2f((unsigned short)(hv.y       )), sc.z, sh.z), 0.f);
            float a3 = fmaxf(fmaf(bf2f((unsigned short)(hv.y >> 16 )), sc.w, sh.w), 0.f);
            float b0 = fmaxf(fmaf(bf2f((unsigned short)(hv.z       )), sc.x, sh.x), 0.f);
            float b1 = fmaxf(fmaf(bf2f((unsigned short)(hv.z >> 16 )), sc.y, sh.y), 0.f);
            float b2 = fmaxf(fmaf(bf2f((unsigned short)(hv.w       )), sc.z, sh.z), 0.f);
            float b3 = fmaxf(fmaf(bf2f((unsigned short)(hv.w >> 16 )), sc.w, sh.w), 0.f);
            *(unsigned long long*)&B4[rowa*520 + o0]        = pack4bf(a0, a1, a2, a3);
            *(unsigned long long*)&B4[(rowa + 16)*520 + o0] = pack4bf(b0, b1, b2, b3);
        }
    }
    if (t < 64) icnt[t >> 5][t & 31] = 0;
    __syncthreads();

    const int wave = t >> 6;
    const int lane = t & 63;
    const int m    = lane & 15;
    const int quad = lane >> 4;

    f32x4 acc4[2][4];
    #pragma unroll
    for (int mt = 0; mt < 2; ++mt)
        #pragma unroll
        for (int n = 0; n < 4; ++n)
            acc4[mt][n] = (f32x4){0.f, 0.f, 0.f, 0.f};

    #pragma unroll 4
    for (int kt = 0; kt < 16; ++kt) {
        s16x8 bv[4];
        #pragma unroll
        for (int nt = 0; nt < 4; ++nt)
            bv[nt] = *(const s16x8*)&B4[(nt*16 + m)*520 + kt*32 + quad*8];
        #pragma unroll
        for (int mt = 0; mt < 2; ++mt) {
            s16x8 av = *(const s16x8*)(W4b + (size_t)(wave*32 + mt*16 + m)*512 + kt*32 + quad*8);
            #pragma unroll
            for (int nt = 0; nt < 4; ++nt)
                acc4[mt][nt] = __builtin_amdgcn_mfma_f32_16x16x32_bf16(av, bv[nt], acc4[mt][nt], 0, 0, 0);
        }
    }

    #pragma unroll
    for (int mt = 0; mt < 2; ++mt) {
        const int o0 = wave*32 + mt*16 + quad*4;
        float f0[4], f1[4];
        #pragma unroll
        for (int r = 0; r < 4; ++r) {
            float bb = b4[o0 + r];
            #pragma unroll
            for (int nt = 0; nt < 4; ++nt) acc4[mt][nt][r] += bb;
            f0[r] = fmaxf(acc4[mt][0][r], acc4[mt][1][r]);
            f1[r] = fmaxf(acc4[mt][2][r], acc4[mt][3][r]);
        }
        #pragma unroll
        for (int msk = 1; msk < 16; msk <<= 1)
            #pragma unroll
            for (int r = 0; r < 4; ++r) {
                f0[r] = fmaxf(f0[r], __shfl_xor(f0[r], msk, 16));
                f1[r] = fmaxf(f1[r], __shfl_xor(f1[r], msk, 16));
            }
        if (m == 0) {
            #pragma unroll
            for (int r = 0; r < 4; ++r) {
                fg2[(size_t)g0*384 + o0 + r]     = f0[r];
                fg2[(size_t)(g0+1)*384 + o0 + r] = f1[r];
            }
        }
    }
    __syncthreads();

    #pragma unroll
    for (int mt = 0; mt < 2; ++mt) {
        const int o0 = wave*32 + mt*16 + quad*4;
        #pragma unroll
        for (int nt = 0; nt < 4; ++nt) {
            const int g = nt >> 1;
            const int l = (nt & 1)*16 + m;
            unsigned short* xg = XT + g*15360;
            #pragma unroll
            for (int r = 0; r < 4; ++r)
                xg[(o0 + r)*40 + l] = f2bf(acc4[mt][nt][r]);
        }
    }
    if (t < 64) {
        const int g = t >> 5, l = t & 31;
        uint4 z = make_uint4(0u, 0u, 0u, 0u);
        #pragma unroll
        for (int i = 0; i < 5; ++i)
            *(uint4*)&Mm[g*1280 + l*40 + i*8] = z;
    }
    __syncthreads();

    if (t < 64) {
        const int g = t >> 5, l = t & 31;
        const int* ip = idxw + (size_t)(g0 + g)*256 + l*8;
        #pragma unroll
        for (int j = 0; j < 8; ++j) {
            int ix = ip[j];
            Mm[g*1280 + l*40 + ix] = 0x3F80;
            atomicAdd(&icnt[g][ix], 1);
        }
    }
    __syncthreads();

    float s1loc[2] = {0.f, 0.f}, s2loc[2] = {0.f, 0.f};
    #pragma unroll
    for (int g = 0; g < 2; ++g) {
        const float c0 = (float)icnt[g][m];
        const float c1 = (float)icnt[g][m + 16];
        const float w0 = c0 - 8.f, u0 = c0 + 8.f;
        const float w1 = c1 - 8.f, u1 = c1 + 8.f;
        #pragma unroll
        for (int mt = 0; mt < 2; ++mt) {
            const int o0 = wave*32 + mt*16 + quad*4;
            float Ap[4];
            #pragma unroll
            for (int r = 0; r < 4; ++r) {
                const float x0 = acc4[mt][g*2 + 0][r];
                const float x1 = acc4[mt][g*2 + 1][r];
                Ap[r] = w0*x0 + w1*x1;
                s1loc[g] += Ap[r];
                s2loc[g] += u0*x0*x0 + u1*x1*x1;
            }
            #pragma unroll
            for (int msk = 1; msk < 16; msk <<= 1)
                #pragma unroll
                for (int r = 0; r < 4; ++r)
                    Ap[r] += __shfl_xor(Ap[r], msk, 16);
            if (m == 0) {
                #pragma unroll
                for (int r = 0; r < 4; ++r)
                    A[(size_t)(g0 + g)*384 + o0 + r] = Ap[r];
            }
        }
    }

    #pragma unroll
    for (int g = 0; g < 2; ++g) {
        const unsigned short* xg = XT + g*15360;
        float cross = 0.f;
        #pragma unroll
        for (int lt = 0; lt < 2; ++lt) {
            s16x8 af = *(const s16x8*)&Mm[g*1280 + (lt*16 + m)*40 + quad*8];
            #pragma unroll
            for (int i = 0; i < 2; ++i) {
                const int oc = (wave*2 + i)*16 + m;
                s16x8 bfv = *(const s16x8*)&xg[oc*40 + quad*8];
                f32x4 sa = __builtin_amdgcn_mfma_f32_16x16x32_bf16(
                    af, bfv, (f32x4){0.f, 0.f, 0.f, 0.f}, 0, 0, 0);
                #pragma unroll
                for (int r = 0; r < 4; ++r) {
                    const int lp = lt*16 + quad*4 + r;
                    cross = fmaf(bf2f(xg[oc*40 + lp]), sa[r], cross);
                }
            }
        }
        s2loc[g] -= 2.f * cross;
    }

    #pragma unroll
    for (int g = 0; g < 2; ++g) {
        float sA = s1loc[g], sQ = s2loc[g];
        #pragma unroll
        for (int off = 32; off > 0; off >>= 1) {
            sA += __shfl_down(sA, off, 64);
            sQ += __shfl_down(sQ, off, 64);
        }
        if (lane == 0) { r1[g][wave] = sA; r2[g][wave] = sQ; }
    }
    __syncthreads();
    if (t < 2) {
        float S = 0.f, Q = 0.f;
        #pragma unroll
        for (int w = 0; w < 12; ++w) { S += r1[t][w]; Q += r2[t][w]; }
        S1p[g0 + t] = S;
        S2p[g0 + t] = Q;
    }
}

// ---------------------------------------------------------------- K7: fused head MFMA GEMM, N=16 groups/block, grid 64. Inlines k6 std.
__global__ __launch_bounds__(384) void k7_fused(
    const float* __restrict__ fg2, const float* __restrict__ A,
    const float* __restrict__ alpha, const float* __restrict__ beta_aff,
    const float* __restrict__ S1p, const float* __restrict__ S2p,
    const unsigned short* __restrict__ Wfb, const float* __restrict__ bf,
    float* __restrict__ hf, float* __restrict__ pfs, float* __restrict__ pfq)
{
    const int blk = blockIdx.x;
    const int g0 = blk * 16;
    const int t = threadIdx.x;
    __shared__ __align__(16) char smem[24832];
    unsigned short* xfb = (unsigned short*)smem;   // [16][776]
    float* OTf = (float*)smem;                     // [16][388]
    __shared__ double rs[6], rq[6];
    __shared__ float stdsh;

    {
        double s = 0.0, q = 0.0;
        for (int i = t; i < 1024; i += 384) { s += (double)S1p[i]; q += (double)S2p[i]; }
        #pragma unroll
        for (int off = 32; off > 0; off >>= 1) {
            s += __shfl_down(s, off, 64);
            q += __shfl_down(q, off, 64);
        }
        if ((t & 63) == 0) { rs[t >> 6] = s; rq[t >> 6] = q; }
        __syncthreads();
        if (t == 0) {
            double S = 0.0, Q = 0.0;
            #pragma unroll
            for (int w = 0; w < 6; ++w) { S += rs[w]; Q += rq[w]; }
            const double N = 1024.0 * 32.0 * 8.0 * 384.0;
            double var = (Q - S*S/N) / (N - 1.0);
            stdsh = (float)sqrt(var);
        }
        __syncthreads();
    }
    const float inv = 1.f / (256.f * (stdsh + EPS));

    for (int i = t; i < 16*96; i += 384) {
        const int row = i / 96, c8 = (i % 96) * 8;
        const int g = g0 + row;
        float e[8];
        if (c8 < 384) {
            const float4* s0 = (const float4*)(fg2 + (size_t)g*384 + c8);
            float4 v0 = s0[0], v1 = s0[1];
            e[0]=v0.x; e[1]=v0.y; e[2]=v0.z; e[3]=v0.w;
            e[4]=v1.x; e[5]=v1.y; e[6]=v1.z; e[7]=v1.w;
        } else {
            const int cc = c8 - 384;
            const float4* s0 = (const float4*)(A + (size_t)g*384 + cc);
            float4 v0 = s0[0], v1 = s0[1];
            float av[8] = {v0.x,v0.y,v0.z,v0.w,v1.x,v1.y,v1.z,v1.w};
            #pragma unroll
            for (int j = 0; j < 8; ++j)
                e[j] = fmaf(alpha[cc+j] * inv, av[j], beta_aff[cc+j]);
        }
        uint4 o4;
        o4.x = (unsigned)f2bf(e[0]) | ((unsigned)f2bf(e[1]) << 16);
        o4.y = (unsigned)f2bf(e[2]) | ((unsigned)f2bf(e[3]) << 16);
        o4.z = (unsigned)f2bf(e[4]) | ((unsigned)f2bf(e[5]) << 16);
        o4.w = (unsigned)f2bf(e[6]) | ((unsigned)f2bf(e[7]) << 16);
        *(uint4*)&xfb[row*776 + c8] = o4;
    }
    __syncthreads();

    const int wave = t >> 6;
    const int lane = t & 63;
    const int m    = lane & 15;
    const int quad = lane >> 4;

    f32x4 acc[4];
    #pragma unroll
    for (int mt = 0; mt < 4; ++mt) acc[mt] = (f32x4){0.f, 0.f, 0.f, 0.f};

    #pragma unroll 4
    for (int kt = 0; kt < 24; ++kt) {
        s16x8 bv = *(const s16x8*)&xfb[m*776 + kt*32 + quad*8];
        #pragma unroll
        for (int mt = 0; mt < 4; ++mt) {
            s16x8 av = *(const s16x8*)(Wfb + (size_t)(wave*64 + mt*16 + m)*768 + kt*32 + quad*8);
            acc[mt] = __builtin_amdgcn_mfma_f32_16x16x32_bf16(av, bv, acc[mt], 0, 0, 0);
        }
    }

    #pragma unroll
    for (int mt = 0; mt < 4; ++mt) {
        const int o0 = wave*64 + mt*16 + quad*4;
        float s[4], q[4];
        #pragma unroll
        for (int r = 0; r < 4; ++r) {
            acc[mt][r] += bf[o0 + r];
            s[r] = acc[mt][r];
            q[r] = acc[mt][r]*acc[mt][r];
        }
        #pragma unroll
        for (int msk = 1; msk < 16; msk <<= 1)
            #pragma unroll
            for (int r = 0; r < 4; ++r) {
                s[r] += __shfl_xor(s[r], msk, 16);
                q[r] += __shfl_xor(q[r], msk, 16);
            }
        if (m == 0) {
            #pragma unroll
            for (int r = 0; r < 4; ++r) {
                pfs[(size_t)blk*384 + o0 + r] = s[r];
                pfq[(size_t)blk*384 + o0 + r] = q[r];
            }
        }
    }
    __syncthreads();

    #pragma unroll
    for (int mt = 0; mt < 4; ++mt) {
        const int o0 = wave*64 + mt*16 + quad*4;
        #pragma unroll
        for (int r = 0; r < 4; ++r)
            OTf[m*388 + o0 + r] = acc[mt][r];
    }
    __syncthreads();

    {
        float* dst = hf + (size_t)g0*384;
        #pragma unroll
        for (int k = 0; k < 4; ++k) {
            const int i = t + k*384;
            const int row = i / 96;
            float4 v = *(const float4*)&OTf[i*4 + row*4];
            *(float4*)(dst + i*4) = v;
        }
    }
}

// ---------------------------------------------------------------- K9: BNf + relu -> out
__global__ __launch_bounds__(384) void k9_out(
    const float* __restrict__ hf, const float* __restrict__ scalef,
    const float* __restrict__ shiftf, float* __restrict__ out)
{
    const int b = blockIdx.x, t = threadIdx.x;
    float v = fmaf(hf[(size_t)b*384 + t], scalef[t], shiftf[t]);
    out[(size_t)b*384 + t] = fmaxf(v, 0.f);
}

extern "C" void kernel_launch(void* const* d_in, const int* in_sizes, int n_in,
                              void* d_out, int out_size, void* d_ws, size_t ws_size,
                              hipStream_t stream) {
    const float* pg      = (const float*)d_in[0];
    const float* W1      = (const float*)d_in[1];
    const float* b1      = (const float*)d_in[2];
    const float* gamma1  = (const float*)d_in[3];
    const float* beta1   = (const float*)d_in[4];
    const float* W2      = (const float*)d_in[5];
    const float* b2      = (const float*)d_in[6];
    const float* W3      = (const float*)d_in[7];
    const float* b3      = (const float*)d_in[8];
    const float* gamma3  = (const float*)d_in[9];
    const float* beta3   = (const float*)d_in[10];
    const float* W4      = (const float*)d_in[11];
    const float* b4      = (const float*)d_in[12];
    const float* alpha   = (const float*)d_in[13];
    const float* beta_af = (const float*)d_in[14];
    const float* Wf      = (const float*)d_in[15];
    const float* bf      = (const float*)d_in[16];
    const float* gammaf  = (const float*)d_in[17];
    const float* betaf   = (const float*)d_in[18];
    float* out = (float*)d_out;

    float* w = (float*)d_ws;
    unsigned short* h1b = (unsigned short*)w; w += 1024*4096/2;       // 8 MB bf16 [b][l][c]
    unsigned short* h3b = (unsigned short*)w; w += 1024*16384/2;      // 32 MB bf16, fragment order
    unsigned short* W2b = (unsigned short*)w; w += 32768/2;
    unsigned short* W3b = (unsigned short*)w; w += 262144/2;
    unsigned short* W4b = (unsigned short*)w; w += 196608/2;
    unsigned short* Wfb = (unsigned short*)w; w += 294912/2;
    float* hf     = w;  w += 1024*384;
    float* fg2    = w;  w += 1024*384;
    float* A      = w;  w += 1024*384;
    float* p1s    = w;  w += 1024*128;   // [b][c]
    float* p1q    = w;  w += 1024*128;
    float* p3s    = w;  w += 1024*512;   // [g][o]
    float* p3q    = w;  w += 1024*512;
    float* pfs    = w;  w += 64*384;     // [blk][o]
    float* pfq    = w;  w += 64*384;
    float* S1p    = w;  w += 1024;
    float* S2p    = w;  w += 1024;
    float* scale1 = w;  w += 128;
    float* shift1 = w;  w += 128;
    float* scale3 = w;  w += 512;
    float* shift3 = w;  w += 512;
    float* scalef = w;  w += 384;
    float* shiftf = w;  w += 384;
    int*   idxw   = (int*)w;  w += 1024*256;

    hipLaunchKernelGGL(k1_conv1_knn, dim3(1024 + 2304), dim3(128), 0, stream,
                       pg, W1, b1, W2, W3, W4, Wf,
                       h1b, p1s, p1q, idxw, W2b, W3b, W4b, Wfb);
    hipLaunchKernelGGL(k_bn_fin2, dim3(32), dim3(256), 0, stream,
                       p1s, p1q, 1024, 128, 1.f/32768.f, gamma1, beta1, scale1, shift1);
    hipLaunchKernelGGL(k3_mfma, dim3(512), dim3(1024), 0, stream,
                       h1b, scale1, shift1, W2b, b2, W3b, b3, h3b, p3s, p3q);
    hipLaunchKernelGGL(k_bn_fin2, dim3(128), dim3(256), 0, stream,
                       p3s, p3q, 1024, 512, 1.f/32768.f, gamma3, beta3, scale3, shift3);
    hipLaunchKernelGGL(k5_mfma, dim3(512), dim3(768), 0, stream,
                       h3b, scale3, shift3, W4b, b4, idxw, fg2, A, S1p, S2p);
    hipLaunchKernelGGL(k7_fused, dim3(64), dim3(384), 0, stream,
                       fg2, A, alpha, beta_af, S1p, S2p, Wfb, bf, hf, pfs, pfq);
    hipLaunchKernelGGL(k_bn_fin2, dim3(96), dim3(256), 0, stream,
                       pfs, pfq, 64, 384, 1.f/1024.f, gammaf, betaf, scalef, shiftf);
    hipLaunchKernelGGL(k9_out, dim3(1024), dim3(384), 0, stream,
                       hf, scalef, shiftf, out);
}

// Round 9
// 233.824 us; speedup vs baseline: 1.0206x; 1.0206x over previous
//
#include <hip/hip_runtime.h>
#include <math.h>

#define EPS 1e-5f

typedef __attribute__((ext_vector_type(8))) short s16x8;   // 8 bf16 (4 VGPRs)
typedef __attribute__((ext_vector_type(4))) float f32x4;   // MFMA C/D

__device__ __forceinline__ unsigned short f2bf(float x) {
    unsigned u = __float_as_uint(x);
    u += 0x7fffu + ((u >> 16) & 1u);           // round-to-nearest-even
    return (unsigned short)(u >> 16);
}
__device__ __forceinline__ float bf2f(unsigned short h) {
    return __uint_as_float(((unsigned)h) << 16);
}
__device__ __forceinline__ unsigned long long pack4bf(float a, float b, float c, float d) {
    return (unsigned long long)f2bf(a)
         | ((unsigned long long)f2bf(b) << 16)
         | ((unsigned long long)f2bf(c) << 32)
         | ((unsigned long long)f2bf(d) << 48);
}

// ---------------------------------------------------------------- K1: conv1 + knn + (fused) weight bf16 conversion
// h1b bf16 [b][l][c]. grid 1024 + 2304 (weight-convert blocks).
__global__ __launch_bounds__(128) void k1_conv1_knn(
    const float* __restrict__ pg, const float* __restrict__ W1,
    const float* __restrict__ b1,
    const float* __restrict__ W2, const float* __restrict__ W3,
    const float* __restrict__ W4, const float* __restrict__ Wf,
    unsigned short* __restrict__ h1b, float* __restrict__ p1s, float* __restrict__ p1q,
    int* __restrict__ idxw,
    unsigned short* __restrict__ W2b, unsigned short* __restrict__ W3b,
    unsigned short* __restrict__ W4b, unsigned short* __restrict__ Wfb)
{
    __shared__ float pgs[96];
    __shared__ float sqs[32];
    if (blockIdx.x >= 1024) {
        const int i = (blockIdx.x - 1024) * 128 + threadIdx.x;
        if (i < 32768)  W2b[i] = f2bf(W2[i]);
        if (i < 262144) W3b[i] = f2bf(W3[i]);
        if (i < 196608) W4b[i] = f2bf(W4[i]);
        if (i < 294912) Wfb[i] = f2bf(Wf[i]);
        return;
    }
    const int b = blockIdx.x;
    const int t = threadIdx.x;
    if (t < 96) pgs[t] = pg[b * 96 + t];
    __syncthreads();
    if (t < 32) {
        float x = pgs[t*3+0], y = pgs[t*3+1], z = pgs[t*3+2];
        sqs[t] = x*x + y*y + z*z;
    }
    __syncthreads();
    {
        const float w0 = W1[t*3+0], w1 = W1[t*3+1], w2 = W1[t*3+2];
        const float bb = b1[t];
        float s = 0.f, q = 0.f;
        unsigned short* hcol = h1b + (size_t)b*4096 + t;
        #pragma unroll
        for (int l = 0; l < 32; ++l) {
            float v = fmaf(w2, pgs[l*3+2], fmaf(w1, pgs[l*3+1], fmaf(w0, pgs[l*3+0], bb)));
            hcol[l*128] = f2bf(v); s += v; q += v*v;
        }
        p1s[b*128 + t] = s;
        p1q[b*128 + t] = q;
    }
    if (t < 32) {
        const float xl = pgs[t*3+0], yl = pgs[t*3+1], zl = pgs[t*3+2];
        const float sql = sqs[t];
        float dist[32];
        #pragma unroll
        for (int m = 0; m < 32; ++m) {
            float dot = xl*pgs[m*3+0] + yl*pgs[m*3+1] + zl*pgs[m*3+2];
            dist[m] = sql + sqs[m] - 2.f*dot;
        }
        unsigned used = 0u;
        int* orow = idxw + b*256 + t*8;
        #pragma unroll
        for (int j = 0; j < 8; ++j) {
            float best = 3.4e38f; int bi = 0;
            #pragma unroll
            for (int m = 0; m < 32; ++m) {
                if (!((used >> m) & 1u) && dist[m] < best) { best = dist[m]; bi = m; }
            }
            used |= (1u << bi);
            orow[j] = bi;
        }
    }
}

// ---------------------------------------------------------------- BN finalize, partials [part][chan], 4 channels/block
__global__ __launch_bounds__(256) void k_bn_fin2(
    const float* __restrict__ ps, const float* __restrict__ pq,
    int nPart, int nChan, float invN,
    const float* __restrict__ gamma, const float* __restrict__ beta,
    float* __restrict__ scale, float* __restrict__ shift)
{
    const int ob = blockIdx.x * 4;
    const int t = threadIdx.x;
    const int co = t & 3, i0 = t >> 2;
    float s = 0.f, q = 0.f;
    for (int i = i0; i < nPart; i += 64) {
        s += ps[(size_t)i*nChan + ob + co];
        q += pq[(size_t)i*nChan + ob + co];
    }
    #pragma unroll
    for (int off = 32; off >= 4; off >>= 1) {
        s += __shfl_down(s, off, 64);
        q += __shfl_down(q, off, 64);
    }
    __shared__ float ss[4][4], qs[4][4];
    const int wid = t >> 6, lane = t & 63;
    if (lane < 4) { ss[wid][lane] = s; qs[wid][lane] = q; }
    __syncthreads();
    if (t < 4) {
        float S = ss[0][t] + ss[1][t] + ss[2][t] + ss[3][t];
        float Q = qs[0][t] + qs[1][t] + qs[2][t] + qs[3][t];
        const int o = ob + t;
        float mu  = S * invN;
        float var = Q * invN - mu*mu;
        float sc  = gamma[o] * rsqrtf(var + EPS);
        scale[o] = sc;
        shift[o] = beta[o] - mu * sc;
    }
}

// ---------------------------------------------------------------- K3 (R7 shape): 2 groups/block, 8 waves (512 thr), bf16 h1b input.
// conv2 (K=128, 2mt) -> fg-bias GEMM (4 tiles) -> conv3 main (K=256, 4mt).
__global__ __launch_bounds__(512, 2) void k3_mfma(
    const unsigned short* __restrict__ h1b,
    const float* __restrict__ scale1, const float* __restrict__ shift1,
    const unsigned short* __restrict__ W2b, const float* __restrict__ b2,
    const unsigned short* __restrict__ W3b, const float* __restrict__ b3,
    unsigned short* __restrict__ h3b, float* __restrict__ p3s, float* __restrict__ p3q)
{
    const int g0 = blockIdx.x * 2;
    const int t = threadIdx.x;
    __shared__ __align__(16) unsigned short SB[19472];
    unsigned short* B1  = SB;            // [64][136] conv2 staging (dead after conv2)
    unsigned short* F2  = SB;            // [64][264] f2, conv3 B-matrix
    unsigned short* FGB = SB + 16896;    // [2][264] fg per group (bf16)
    float* FGR = (float*)(SB + 17424);   // [512][2] fg-bias result fp32

    // ---- P0: stage x1 = relu(BN1(h1b)) bf16 [l64][c128]; 2 x 16B per thread
    {
        const int l = t >> 3, c0 = (t & 7) * 16;
        const int g = g0 + (l >> 5);
        #pragma unroll
        for (int h = 0; h < 2; ++h) {
            s16x8 hv = *(const s16x8*)(h1b + (size_t)g*4096 + (l & 31)*128 + c0 + h*8);
            unsigned short ov[8];
            #pragma unroll
            for (int e = 0; e < 8; ++e) {
                int c = c0 + h*8 + e;
                float v = fmaxf(fmaf(bf2f((unsigned short)hv[e]), scale1[c], shift1[c]), 0.f);
                ov[e] = f2bf(v);
            }
            uint4 o4;
            o4.x = (unsigned)ov[0] | ((unsigned)ov[1] << 16);
            o4.y = (unsigned)ov[2] | ((unsigned)ov[3] << 16);
            o4.z = (unsigned)ov[4] | ((unsigned)ov[5] << 16);
            o4.w = (unsigned)ov[6] | ((unsigned)ov[7] << 16);
            *(uint4*)&B1[l*136 + c0 + h*8] = o4;
        }
    }
    __syncthreads();

    const int wave = t >> 6;      // 0..7
    const int lane = t & 63;
    const int m    = lane & 15;
    const int quad = lane >> 4;

    // ---- P1: conv2 MFMA: M=256 (2 mt/wave), N=64, K=128
    f32x4 acc2[2][4];
    #pragma unroll
    for (int mt = 0; mt < 2; ++mt)
        #pragma unroll
        for (int n = 0; n < 4; ++n)
            acc2[mt][n] = (f32x4){0.f, 0.f, 0.f, 0.f};

    #pragma unroll
    for (int kt = 0; kt < 4; ++kt) {
        s16x8 bv[4];
        #pragma unroll
        for (int nt = 0; nt < 4; ++nt)
            bv[nt] = *(const s16x8*)&B1[(nt*16 + m)*136 + kt*32 + quad*8];
        #pragma unroll
        for (int mt = 0; mt < 2; ++mt) {
            s16x8 av = *(const s16x8*)(W2b + (size_t)(wave*32 + mt*16 + m)*128 + kt*32 + quad*8);
            #pragma unroll
            for (int nt = 0; nt < 4; ++nt)
                acc2[mt][nt] = __builtin_amdgcn_mfma_f32_16x16x32_bf16(av, bv[nt], acc2[mt][nt], 0, 0, 0);
        }
    }
    __syncthreads();   // B1 dead; SB becomes F2

    // ---- P2: epilogue conv2: bias, write f2 cols, fg into FGB
    #pragma unroll
    for (int mt = 0; mt < 2; ++mt) {
        const int o0 = wave*32 + mt*16 + quad*4;
        #pragma unroll
        for (int r = 0; r < 4; ++r) {
            float bb = b2[o0 + r];
            #pragma unroll
            for (int nt = 0; nt < 4; ++nt) acc2[mt][nt][r] += bb;
        }
        #pragma unroll
        for (int nt = 0; nt < 4; ++nt) {
            const int row = nt*16 + m;
            *(unsigned long long*)&F2[row*264 + o0] =
                pack4bf(acc2[mt][nt][0], acc2[mt][nt][1], acc2[mt][nt][2], acc2[mt][nt][3]);
        }
        float f0[4], f1[4];
        #pragma unroll
        for (int r = 0; r < 4; ++r) {
            f0[r] = fmaxf(acc2[mt][0][r], acc2[mt][1][r]);
            f1[r] = fmaxf(acc2[mt][2][r], acc2[mt][3][r]);
        }
        #pragma unroll
        for (int msk = 1; msk < 16; msk <<= 1)
            #pragma unroll
            for (int r = 0; r < 4; ++r) {
                f0[r] = fmaxf(f0[r], __shfl_xor(f0[r], msk, 16));
                f1[r] = fmaxf(f1[r], __shfl_xor(f1[r], msk, 16));
            }
        if (m == 0) {
            *(unsigned long long*)&FGB[o0]       = pack4bf(f0[0], f0[1], f0[2], f0[3]);
            *(unsigned long long*)&FGB[264 + o0] = pack4bf(f1[0], f1[1], f1[2], f1[3]);
        }
    }
    __syncthreads();

    // ---- P3: fg-bias GEMM: fgb[o][g] = W3[:, :256] . fg[g]; 4 tiles/wave, K=256
    {
        f32x4 facc[4];
        #pragma unroll
        for (int i = 0; i < 4; ++i) facc[i] = (f32x4){0.f, 0.f, 0.f, 0.f};
        #pragma unroll
        for (int kt = 0; kt < 8; ++kt) {
            s16x8 bg = *(const s16x8*)&FGB[(m & 1)*264 + kt*32 + quad*8];
            #pragma unroll
            for (int i = 0; i < 4; ++i) {
                s16x8 av = *(const s16x8*)(W3b + (size_t)((wave*4 + i)*16 + m)*512 + kt*32 + quad*8);
                facc[i] = __builtin_amdgcn_mfma_f32_16x16x32_bf16(av, bg, facc[i], 0, 0, 0);
            }
        }
        if (m < 2) {
            #pragma unroll
            for (int i = 0; i < 4; ++i)
                #pragma unroll
                for (int r = 0; r < 4; ++r)
                    FGR[((wave*4 + i)*16 + quad*4 + r)*2 + m] = facc[i][r];
        }
    }
    __syncthreads();

    // ---- P4: conv3 main: 4 mt/wave, N=64, K=256; acc init = b3 + fgb
    f32x4 acc3[4][4];
    #pragma unroll
    for (int mt = 0; mt < 4; ++mt) {
        const int ob = (wave*4 + mt)*16 + quad*4;
        #pragma unroll
        for (int r = 0; r < 4; ++r) {
            float2 fb = *(const float2*)&FGR[(ob + r)*2];
            float bb = b3[ob + r];
            acc3[mt][0][r] = bb + fb.x;
            acc3[mt][1][r] = bb + fb.x;
            acc3[mt][2][r] = bb + fb.y;
            acc3[mt][3][r] = bb + fb.y;
        }
    }
    #pragma unroll 4
    for (int kt = 0; kt < 8; ++kt) {
        s16x8 bv[4];
        #pragma unroll
        for (int nt = 0; nt < 4; ++nt)
            bv[nt] = *(const s16x8*)&F2[(nt*16 + m)*264 + kt*32 + quad*8];
        #pragma unroll
        for (int mt = 0; mt < 4; ++mt) {
            s16x8 av = *(const s16x8*)(W3b + (size_t)((wave*4 + mt)*16 + m)*512 + 256 + kt*32 + quad*8);
            #pragma unroll
            for (int nt = 0; nt < 4; ++nt)
                acc3[mt][nt] = __builtin_amdgcn_mfma_f32_16x16x32_bf16(av, bv[nt], acc3[mt][nt], 0, 0, 0);
        }
    }

    // ---- epilogue: fragment-order h3b store (ot = wave*4+mt) + stats
    unsigned short* dst = h3b + (size_t)blockIdx.x * 32768;
    #pragma unroll
    for (int mt = 0; mt < 4; ++mt) {
        const int ot = wave*4 + mt;
        const int o0 = ot*16 + quad*4;
        float s0[4], q0[4], s1[4], q1[4];
        #pragma unroll
        for (int r = 0; r < 4; ++r) {
            s0[r] = acc3[mt][0][r] + acc3[mt][1][r];
            q0[r] = acc3[mt][0][r]*acc3[mt][0][r] + acc3[mt][1][r]*acc3[mt][1][r];
            s1[r] = acc3[mt][2][r] + acc3[mt][3][r];
            q1[r] = acc3[mt][2][r]*acc3[mt][2][r] + acc3[mt][3][r]*acc3[mt][3][r];
        }
        {
            unsigned long long u0 = pack4bf(acc3[mt][0][0], acc3[mt][0][1], acc3[mt][0][2], acc3[mt][0][3]);
            unsigned long long u1 = pack4bf(acc3[mt][1][0], acc3[mt][1][1], acc3[mt][1][2], acc3[mt][1][3]);
            unsigned long long u2 = pack4bf(acc3[mt][2][0], acc3[mt][2][1], acc3[mt][2][2], acc3[mt][2][3]);
            unsigned long long u3 = pack4bf(acc3[mt][3][0], acc3[mt][3][1], acc3[mt][3][2], acc3[mt][3][3]);
            unsigned short* p = dst + (size_t)(ot*64 + lane) * 16;
            *(uint4*)(p)     = make_uint4((unsigned)u0, (unsigned)(u0 >> 32), (unsigned)u1, (unsigned)(u1 >> 32));
            *(uint4*)(p + 8) = make_uint4((unsigned)u2, (unsigned)(u2 >> 32), (unsigned)u3, (unsigned)(u3 >> 32));
        }
        #pragma unroll
        for (int msk = 1; msk < 16; msk <<= 1)
            #pragma unroll
            for (int r = 0; r < 4; ++r) {
                s0[r] += __shfl_xor(s0[r], msk, 16);
                q0[r] += __shfl_xor(q0[r], msk, 16);
                s1[r] += __shfl_xor(s1[r], msk, 16);
                q1[r] += __shfl_xor(q1[r], msk, 16);
            }
        if (m == 0) {
            #pragma unroll
            for (int r = 0; r < 4; ++r) {
                p3s[(size_t)g0*512 + o0 + r]       = s0[r];
                p3q[(size_t)g0*512 + o0 + r]       = q0[r];
                p3s[(size_t)(g0+1)*512 + o0 + r]   = s1[r];
                p3q[(size_t)(g0+1)*512 + o0 + r]   = q1[r];
            }
        }
    }
}

// ---------------------------------------------------------------- K5: 2 groups/block, 12 waves. MFMA conv4 + fg2 + algebraic knn branch.
__global__ __launch_bounds__(768, 2) void k5_mfma(
    const unsigned short* __restrict__ h3b,
    const float* __restrict__ scale3, const float* __restrict__ shift3,
    const unsigned short* __restrict__ W4b, const float* __restrict__ b4,
    const int* __restrict__ idxw,
    float* __restrict__ fg2, float* __restrict__ A,
    float* __restrict__ S1p, float* __restrict__ S2p)
{
    const int g0 = blockIdx.x * 2;
    const int t = threadIdx.x;
    __shared__ __align__(16) unsigned short SB[33280];   // 66560 B
    unsigned short* B4 = SB;                              // [64][520] staging
    unsigned short* XT = SB;                              // [g][o*40 + l], g stride 15360
    unsigned short* Mm = SB + 30720;                      // [g][l*40 + m], g stride 1280
    __shared__ int icnt[2][32];
    __shared__ float r1[2][12], r2[2][12];

    {
        const uint4* src = (const uint4*)(h3b + (size_t)blockIdx.x * 32768);
        for (int i = t; i < 4096; i += 768) {
            uint4 hv = src[i];
            const int flat16 = i >> 1, half = i & 1;
            const int ln = flat16 & 63, m2 = ln & 15, q2 = ln >> 4;
            const int wm = flat16 >> 6;
            const int o0 = wm*16 + q2*4;
            const float4 sc = *(const float4*)(scale3 + o0);
            const float4 sh = *(const float4*)(shift3 + o0);
            const int rowa = (half*2)*16 + m2;
            float a0 = fmaxf(fmaf(bf2f((unsigned short)(hv.x       )), sc.x, sh.x), 0.f);
            float a1 = fmaxf(fmaf(bf2f((unsigned short)(hv.x >> 16 )), sc.y, sh.y), 0.f);
            float a2 = fmaxf(fmaf(bf2f((unsigned short)(hv.y       )), sc.z, sh.z), 0.f);
            float a3 = fmaxf(fmaf(bf2f((unsigned short)(hv.y >> 16 )), sc.w, sh.w), 0.f);
            float b0 = fmaxf(fmaf(bf2f((unsigned short)(hv.z       )), sc.x, sh.x), 0.f);
            float b1 = fmaxf(fmaf(bf2f((unsigned short)(hv.z >> 16 )), sc.y, sh.y), 0.f);
            float b2 = fmaxf(fmaf(bf2f((unsigned short)(hv.w       )), sc.z, sh.z), 0.f);
            float b3 = fmaxf(fmaf(bf2f((unsigned short)(hv.w >> 16 )), sc.w, sh.w), 0.f);
            *(unsigned long long*)&B4[rowa*520 + o0]        = pack4bf(a0, a1, a2, a3);
            *(unsigned long long*)&B4[(rowa + 16)*520 + o0] = pack4bf(b0, b1, b2, b3);
        }
    }
    if (t < 64) icnt[t >> 5][t & 31] = 0;
    __syncthreads();

    const int wave = t >> 6;
    const int lane = t & 63;
    const int m    = lane & 15;
    const int quad = lane >> 4;

    f32x4 acc4[2][4];
    #pragma unroll
    for (int mt = 0; mt < 2; ++mt)
        #pragma unroll
        for (int n = 0; n < 4; ++n)
            acc4[mt][n] = (f32x4){0.f, 0.f, 0.f, 0.f};

    #pragma unroll 4
    for (int kt = 0; kt < 16; ++kt) {
        s16x8 bv[4];
        #pragma unroll
        for (int nt = 0; nt < 4; ++nt)
            bv[nt] = *(const s16x8*)&B4[(nt*16 + m)*520 + kt*32 + quad*8];
        #pragma unroll
        for (int mt = 0; mt < 2; ++mt) {
            s16x8 av = *(const s16x8*)(W4b + (size_t)(wave*32 + mt*16 + m)*512 + kt*32 + quad*8);
            #pragma unroll
            for (int nt = 0; nt < 4; ++nt)
                acc4[mt][nt] = __builtin_amdgcn_mfma_f32_16x16x32_bf16(av, bv[nt], acc4[mt][nt], 0, 0, 0);
        }
    }

    #pragma unroll
    for (int mt = 0; mt < 2; ++mt) {
        const int o0 = wave*32 + mt*16 + quad*4;
        float f0[4], f1[4];
        #pragma unroll
        for (int r = 0; r < 4; ++r) {
            float bb = b4[o0 + r];
            #pragma unroll
            for (int nt = 0; nt < 4; ++nt) acc4[mt][nt][r] += bb;
            f0[r] = fmaxf(acc4[mt][0][r], acc4[mt][1][r]);
            f1[r] = fmaxf(acc4[mt][2][r], acc4[mt][3][r]);
        }
        #pragma unroll
        for (int msk = 1; msk < 16; msk <<= 1)
            #pragma unroll
            for (int r = 0; r < 4; ++r) {
                f0[r] = fmaxf(f0[r], __shfl_xor(f0[r], msk, 16));
                f1[r] = fmaxf(f1[r], __shfl_xor(f1[r], msk, 16));
            }
        if (m == 0) {
            #pragma unroll
            for (int r = 0; r < 4; ++r) {
                fg2[(size_t)g0*384 + o0 + r]     = f0[r];
                fg2[(size_t)(g0+1)*384 + o0 + r] = f1[r];
            }
        }
    }
    __syncthreads();

    #pragma unroll
    for (int mt = 0; mt < 2; ++mt) {
        const int o0 = wave*32 + mt*16 + quad*4;
        #pragma unroll
        for (int nt = 0; nt < 4; ++nt) {
            const int g = nt >> 1;
            const int l = (nt & 1)*16 + m;
            unsigned short* xg = XT + g*15360;
            #pragma unroll
            for (int r = 0; r < 4; ++r)
                xg[(o0 + r)*40 + l] = f2bf(acc4[mt][nt][r]);
        }
    }
    if (t < 64) {
        const int g = t >> 5, l = t & 31;
        uint4 z = make_uint4(0u, 0u, 0u, 0u);
        #pragma unroll
        for (int i = 0; i < 5; ++i)
            *(uint4*)&Mm[g*1280 + l*40 + i*8] = z;
    }
    __syncthreads();

    if (t < 64) {
        const int g = t >> 5, l = t & 31;
        const int* ip = idxw + (size_t)(g0 + g)*256 + l*8;
        #pragma unroll
        for (int j = 0; j < 8; ++j) {
            int ix = ip[j];
            Mm[g*1280 + l*40 + ix] = 0x3F80;
            atomicAdd(&icnt[g][ix], 1);
        }
    }
    __syncthreads();

    float s1loc[2] = {0.f, 0.f}, s2loc[2] = {0.f, 0.f};
    #pragma unroll
    for (int g = 0; g < 2; ++g) {
        const float c0 = (float)icnt[g][m];
        const float c1 = (float)icnt[g][m + 16];
        const float w0 = c0 - 8.f, u0 = c0 + 8.f;
        const float w1 = c1 - 8.f, u1 = c1 + 8.f;
        #pragma unroll
        for (int mt = 0; mt < 2; ++mt) {
            const int o0 = wave*32 + mt*16 + quad*4;
            float Ap[4];
            #pragma unroll
            for (int r = 0; r < 4; ++r) {
                const float x0 = acc4[mt][g*2 + 0][r];
                const float x1 = acc4[mt][g*2 + 1][r];
                Ap[r] = w0*x0 + w1*x1;
                s1loc[g] += Ap[r];
                s2loc[g] += u0*x0*x0 + u1*x1*x1;
            }
            #pragma unroll
            for (int msk = 1; msk < 16; msk <<= 1)
                #pragma unroll
                for (int r = 0; r < 4; ++r)
                    Ap[r] += __shfl_xor(Ap[r], msk, 16);
            if (m == 0) {
                #pragma unroll
                for (int r = 0; r < 4; ++r)
                    A[(size_t)(g0 + g)*384 + o0 + r] = Ap[r];
            }
        }
    }

    #pragma unroll
    for (int g = 0; g < 2; ++g) {
        const unsigned short* xg = XT + g*15360;
        float cross = 0.f;
        #pragma unroll
        for (int lt = 0; lt < 2; ++lt) {
            s16x8 af = *(const s16x8*)&Mm[g*1280 + (lt*16 + m)*40 + quad*8];
            #pragma unroll
            for (int i = 0; i < 2; ++i) {
                const int oc = (wave*2 + i)*16 + m;
                s16x8 bfv = *(const s16x8*)&xg[oc*40 + quad*8];
                f32x4 sa = __builtin_amdgcn_mfma_f32_16x16x32_bf16(
                    af, bfv, (f32x4){0.f, 0.f, 0.f, 0.f}, 0, 0, 0);
                #pragma unroll
                for (int r = 0; r < 4; ++r) {
                    const int lp = lt*16 + quad*4 + r;
                    cross = fmaf(bf2f(xg[oc*40 + lp]), sa[r], cross);
                }
            }
        }
        s2loc[g] -= 2.f * cross;
    }

    #pragma unroll
    for (int g = 0; g < 2; ++g) {
        float sA = s1loc[g], sQ = s2loc[g];
        #pragma unroll
        for (int off = 32; off > 0; off >>= 1) {
            sA += __shfl_down(sA, off, 64);
            sQ += __shfl_down(sQ, off, 64);
        }
        if (lane == 0) { r1[g][wave] = sA; r2[g][wave] = sQ; }
    }
    __syncthreads();
    if (t < 2) {
        float S = 0.f, Q = 0.f;
        #pragma unroll
        for (int w = 0; w < 12; ++w) { S += r1[t][w]; Q += r2[t][w]; }
        S1p[g0 + t] = S;
        S2p[g0 + t] = Q;
    }
}

// ---------------------------------------------------------------- K7: fused head MFMA GEMM, N=16 groups/block, grid 64. Inlines k6 std.
__global__ __launch_bounds__(384) void k7_fused(
    const float* __restrict__ fg2, const float* __restrict__ A,
    const float* __restrict__ alpha, const float* __restrict__ beta_aff,
    const float* __restrict__ S1p, const float* __restrict__ S2p,
    const unsigned short* __restrict__ Wfb, const float* __restrict__ bf,
    float* __restrict__ hf, float* __restrict__ pfs, float* __restrict__ pfq)
{
    const int blk = blockIdx.x;
    const int g0 = blk * 16;
    const int t = threadIdx.x;
    __shared__ __align__(16) char smem[24832];
    unsigned short* xfb = (unsigned short*)smem;   // [16][776]
    float* OTf = (float*)smem;                     // [16][388]
    __shared__ double rs[6], rq[6];
    __shared__ float stdsh;

    {
        double s = 0.0, q = 0.0;
        for (int i = t; i < 1024; i += 384) { s += (double)S1p[i]; q += (double)S2p[i]; }
        #pragma unroll
        for (int off = 32; off > 0; off >>= 1) {
            s += __shfl_down(s, off, 64);
            q += __shfl_down(q, off, 64);
        }
        if ((t & 63) == 0) { rs[t >> 6] = s; rq[t >> 6] = q; }
        __syncthreads();
        if (t == 0) {
            double S = 0.0, Q = 0.0;
            #pragma unroll
            for (int w = 0; w < 6; ++w) { S += rs[w]; Q += rq[w]; }
            const double N = 1024.0 * 32.0 * 8.0 * 384.0;
            double var = (Q - S*S/N) / (N - 1.0);
            stdsh = (float)sqrt(var);
        }
        __syncthreads();
    }
    const float inv = 1.f / (256.f * (stdsh + EPS));

    for (int i = t; i < 16*96; i += 384) {
        const int row = i / 96, c8 = (i % 96) * 8;
        const int g = g0 + row;
        float e[8];
        if (c8 < 384) {
            const float4* s0 = (const float4*)(fg2 + (size_t)g*384 + c8);
            float4 v0 = s0[0], v1 = s0[1];
            e[0]=v0.x; e[1]=v0.y; e[2]=v0.z; e[3]=v0.w;
            e[4]=v1.x; e[5]=v1.y; e[6]=v1.z; e[7]=v1.w;
        } else {
            const int cc = c8 - 384;
            const float4* s0 = (const float4*)(A + (size_t)g*384 + cc);
            float4 v0 = s0[0], v1 = s0[1];
            float av[8] = {v0.x,v0.y,v0.z,v0.w,v1.x,v1.y,v1.z,v1.w};
            #pragma unroll
            for (int j = 0; j < 8; ++j)
                e[j] = fmaf(alpha[cc+j] * inv, av[j], beta_aff[cc+j]);
        }
        uint4 o4;
        o4.x = (unsigned)f2bf(e[0]) | ((unsigned)f2bf(e[1]) << 16);
        o4.y = (unsigned)f2bf(e[2]) | ((unsigned)f2bf(e[3]) << 16);
        o4.z = (unsigned)f2bf(e[4]) | ((unsigned)f2bf(e[5]) << 16);
        o4.w = (unsigned)f2bf(e[6]) | ((unsigned)f2bf(e[7]) << 16);
        *(uint4*)&xfb[row*776 + c8] = o4;
    }
    __syncthreads();

    const int wave = t >> 6;
    const int lane = t & 63;
    const int m    = lane & 15;
    const int quad = lane >> 4;

    f32x4 acc[4];
    #pragma unroll
    for (int mt = 0; mt < 4; ++mt) acc[mt] = (f32x4){0.f, 0.f, 0.f, 0.f};

    #pragma unroll 4
    for (int kt = 0; kt < 24; ++kt) {
        s16x8 bv = *(const s16x8*)&xfb[m*776 + kt*32 + quad*8];
        #pragma unroll
        for (int mt = 0; mt < 4; ++mt) {
            s16x8 av = *(const s16x8*)(Wfb + (size_t)(wave*64 + mt*16 + m)*768 + kt*32 + quad*8);
            acc[mt] = __builtin_amdgcn_mfma_f32_16x16x32_bf16(av, bv, acc[mt], 0, 0, 0);
        }
    }

    #pragma unroll
    for (int mt = 0; mt < 4; ++mt) {
        const int o0 = wave*64 + mt*16 + quad*4;
        float s[4], q[4];
        #pragma unroll
        for (int r = 0; r < 4; ++r) {
            acc[mt][r] += bf[o0 + r];
            s[r] = acc[mt][r];
            q[r] = acc[mt][r]*acc[mt][r];
        }
        #pragma unroll
        for (int msk = 1; msk < 16; msk <<= 1)
            #pragma unroll
            for (int r = 0; r < 4; ++r) {
                s[r] += __shfl_xor(s[r], msk, 16);
                q[r] += __shfl_xor(q[r], msk, 16);
            }
        if (m == 0) {
            #pragma unroll
            for (int r = 0; r < 4; ++r) {
                pfs[(size_t)blk*384 + o0 + r] = s[r];
                pfq[(size_t)blk*384 + o0 + r] = q[r];
            }
        }
    }
    __syncthreads();

    #pragma unroll
    for (int mt = 0; mt < 4; ++mt) {
        const int o0 = wave*64 + mt*16 + quad*4;
        #pragma unroll
        for (int r = 0; r < 4; ++r)
            OTf[m*388 + o0 + r] = acc[mt][r];
    }
    __syncthreads();

    {
        float* dst = hf + (size_t)g0*384;
        #pragma unroll
        for (int k = 0; k < 4; ++k) {
            const int i = t + k*384;
            const int row = i / 96;
            float4 v = *(const float4*)&OTf[i*4 + row*4];
            *(float4*)(dst + i*4) = v;
        }
    }
}

// ---------------------------------------------------------------- K9: fused BNf finalize (redundant per-block) + relu -> out
// grid 128 x 384 threads, 8 groups/block. Each block reduces the 64 pfs/pfq partials
// for its channel t (fixed-i loads fully coalesced across t, L2-hot: 96 KB).
__global__ __launch_bounds__(384) void k9_out(
    const float* __restrict__ hf,
    const float* __restrict__ pfs, const float* __restrict__ pfq,
    const float* __restrict__ gammaf, const float* __restrict__ betaf,
    float* __restrict__ out)
{
    const int blk = blockIdx.x, t = threadIdx.x;
    float S = 0.f, Q = 0.f;
    #pragma unroll 8
    for (int i = 0; i < 64; ++i) {
        S += pfs[(size_t)i*384 + t];
        Q += pfq[(size_t)i*384 + t];
    }
    const float mu  = S * (1.f/1024.f);
    const float var = Q * (1.f/1024.f) - mu*mu;
    const float sc  = gammaf[t] * rsqrtf(var + EPS);
    const float sh  = betaf[t] - mu * sc;
    const size_t base = (size_t)blk * 8 * 384;
    #pragma unroll
    for (int g = 0; g < 8; ++g) {
        float v = fmaf(hf[base + g*384 + t], sc, sh);
        out[base + g*384 + t] = fmaxf(v, 0.f);
    }
}

extern "C" void kernel_launch(void* const* d_in, const int* in_sizes, int n_in,
                              void* d_out, int out_size, void* d_ws, size_t ws_size,
                              hipStream_t stream) {
    const float* pg      = (const float*)d_in[0];
    const float* W1      = (const float*)d_in[1];
    const float* b1      = (const float*)d_in[2];
    const float* gamma1  = (const float*)d_in[3];
    const float* beta1   = (const float*)d_in[4];
    const float* W2      = (const float*)d_in[5];
    const float* b2      = (const float*)d_in[6];
    const float* W3      = (const float*)d_in[7];
    const float* b3      = (const float*)d_in[8];
    const float* gamma3  = (const float*)d_in[9];
    const float* beta3   = (const float*)d_in[10];
    const float* W4      = (const float*)d_in[11];
    const float* b4      = (const float*)d_in[12];
    const float* alpha   = (const float*)d_in[13];
    const float* beta_af = (const float*)d_in[14];
    const float* Wf      = (const float*)d_in[15];
    const float* bf      = (const float*)d_in[16];
    const float* gammaf  = (const float*)d_in[17];
    const float* betaf   = (const float*)d_in[18];
    float* out = (float*)d_out;

    float* w = (float*)d_ws;
    unsigned short* h1b = (unsigned short*)w; w += 1024*4096/2;       // 8 MB bf16 [b][l][c]
    unsigned short* h3b = (unsigned short*)w; w += 1024*16384/2;      // 32 MB bf16, fragment order
    unsigned short* W2b = (unsigned short*)w; w += 32768/2;
    unsigned short* W3b = (unsigned short*)w; w += 262144/2;
    unsigned short* W4b = (unsigned short*)w; w += 196608/2;
    unsigned short* Wfb = (unsigned short*)w; w += 294912/2;
    float* hf     = w;  w += 1024*384;
    float* fg2    = w;  w += 1024*384;
    float* A      = w;  w += 1024*384;
    float* p1s    = w;  w += 1024*128;   // [b][c]
    float* p1q    = w;  w += 1024*128;
    float* p3s    = w;  w += 1024*512;   // [g][o]
    float* p3q    = w;  w += 1024*512;
    float* pfs    = w;  w += 64*384;     // [blk][o]
    float* pfq    = w;  w += 64*384;
    float* S1p    = w;  w += 1024;
    float* S2p    = w;  w += 1024;
    float* scale1 = w;  w += 128;
    float* shift1 = w;  w += 128;
    float* scale3 = w;  w += 512;
    float* shift3 = w;  w += 512;
    int*   idxw   = (int*)w;  w += 1024*256;

    hipLaunchKernelGGL(k1_conv1_knn, dim3(1024 + 2304), dim3(128), 0, stream,
                       pg, W1, b1, W2, W3, W4, Wf,
                       h1b, p1s, p1q, idxw, W2b, W3b, W4b, Wfb);
    hipLaunchKernelGGL(k_bn_fin2, dim3(32), dim3(256), 0, stream,
                       p1s, p1q, 1024, 128, 1.f/32768.f, gamma1, beta1, scale1, shift1);
    hipLaunchKernelGGL(k3_mfma, dim3(512), dim3(512), 0, stream,
                       h1b, scale1, shift1, W2b, b2, W3b, b3, h3b, p3s, p3q);
    hipLaunchKernelGGL(k_bn_fin2, dim3(128), dim3(256), 0, stream,
                       p3s, p3q, 1024, 512, 1.f/32768.f, gamma3, beta3, scale3, shift3);
    hipLaunchKernelGGL(k5_mfma, dim3(512), dim3(768), 0, stream,
                       h3b, scale3, shift3, W4b, b4, idxw, fg2, A, S1p, S2p);
    hipLaunchKernelGGL(k7_fused, dim3(64), dim3(384), 0, stream,
                       fg2, A, alpha, beta_af, S1p, S2p, Wfb, bf, hf, pfs, pfq);
    hipLaunchKernelGGL(k9_out, dim3(128), dim3(384), 0, stream,
                       hf, pfs, pfq, gammaf, betaf, out);
}